// Round 1
// baseline (419.115 us; speedup 1.0000x reference)
//
#include <hip/hip_runtime.h>
#include <hip/hip_bf16.h>

#define EPSF 1e-5f

typedef int v4i __attribute__((ext_vector_type(4)));

static constexpr int BB = 4, TT = 1024, DD = 2048, HH = 8192;
static constexpr int MROWS = BB * TT;                 // 4096
static constexpr long long WCOUNT = (long long)DD * HH; // 16777216 = 2^24 (both weights)

// ---------------------------------------------------------------- helpers

__device__ __forceinline__ void async_copy16(const void* g, void* l) {
  __builtin_amdgcn_global_load_lds(
      (const __attribute__((address_space(1))) unsigned int*)g,
      (__attribute__((address_space(3))) unsigned int*)l,
      16, 0, 0);
}

__device__ __forceinline__ int pack4(float a, float b, float c, float d,
                                     float scale, float lo, float hi) {
  int ia = (int)fminf(fmaxf(rintf(a * scale), lo), hi);
  int ib = (int)fminf(fmaxf(rintf(b * scale), lo), hi);
  int ic = (int)fminf(fmaxf(rintf(c * scale), lo), hi);
  int id = (int)fminf(fmaxf(rintf(d * scale), lo), hi);
  return (ia & 0xff) | ((ib & 0xff) << 8) | ((ic & 0xff) << 16) | ((id & 0xff) << 24);
}

// block of 256 threads = 4 waves
__device__ __forceinline__ float blockMax256(float v) {
  #pragma unroll
  for (int off = 32; off; off >>= 1) v = fmaxf(v, __shfl_down(v, off, 64));
  __shared__ float sm[4];
  int lane = threadIdx.x & 63, wv = threadIdx.x >> 6;
  if (lane == 0) sm[wv] = v;
  __syncthreads();
  return fmaxf(fmaxf(sm[0], sm[1]), fmaxf(sm[2], sm[3]));
}

// ---------------------------------------------------------------- mean|w|

__global__ __launch_bounds__(256) void abs_sum_kernel(
    const float* __restrict__ w1, const float* __restrict__ w2,
    double* __restrict__ sums) {
  const float* w = blockIdx.y ? w2 : w1;
  const float4* w4 = (const float4*)w;
  long long n4 = WCOUNT / 4;
  float s = 0.f;
  for (long long i = (long long)blockIdx.x * blockDim.x + threadIdx.x; i < n4;
       i += (long long)gridDim.x * blockDim.x) {
    float4 v = w4[i];
    s += fabsf(v.x) + fabsf(v.y) + fabsf(v.z) + fabsf(v.w);
  }
  #pragma unroll
  for (int off = 32; off; off >>= 1) s += __shfl_down(s, off, 64);
  __shared__ float sm[4];
  int lane = threadIdx.x & 63, wv = threadIdx.x >> 6;
  if (lane == 0) sm[wv] = s;
  __syncthreads();
  if (threadIdx.x == 0) {
    float t = sm[0] + sm[1] + sm[2] + sm[3];
    atomicAdd(&sums[blockIdx.y], (double)t);
  }
}

// ---------------------------------------------------------------- ternary quant

__global__ __launch_bounds__(256) void quant_w_kernel(
    const float* __restrict__ w1, const float* __restrict__ w2,
    const double* __restrict__ sums,
    signed char* __restrict__ q1, signed char* __restrict__ q2) {
  const float* w = blockIdx.y ? w2 : w1;
  signed char* q = blockIdx.y ? q2 : q1;
  float mean = fmaxf((float)(sums[blockIdx.y] * (1.0 / (double)WCOUNT)), EPSF);
  float scale = 1.0f / mean;
  const float4* w4 = (const float4*)w;
  int* q4 = (int*)q;
  long long n4 = WCOUNT / 4;
  for (long long i = (long long)blockIdx.x * blockDim.x + threadIdx.x; i < n4;
       i += (long long)gridDim.x * blockDim.x) {
    float4 v = w4[i];
    q4[i] = pack4(v.x, v.y, v.z, v.w, scale, -1.f, 1.f);
  }
}

// ---------------------------------------------------------------- act quant (x: rows of 2048)

__global__ __launch_bounds__(256) void quant_x_kernel(
    const float* __restrict__ x, signed char* __restrict__ xq,
    float* __restrict__ ascale) {
  int row = blockIdx.x;
  const float4* xr = (const float4*)(x + (size_t)row * DD);
  int t = threadIdx.x;
  float4 v0 = xr[2 * t], v1 = xr[2 * t + 1];
  float m = fmaxf(fmaxf(fabsf(v0.x), fabsf(v0.y)), fmaxf(fabsf(v0.z), fabsf(v0.w)));
  m = fmaxf(m, fmaxf(fmaxf(fabsf(v1.x), fabsf(v1.y)), fmaxf(fabsf(v1.z), fabsf(v1.w))));
  float am = fmaxf(blockMax256(m), EPSF);
  float scale = 127.0f / am;
  int* out = (int*)(xq + (size_t)row * DD);
  out[2 * t]     = pack4(v0.x, v0.y, v0.z, v0.w, scale, -128.f, 127.f);
  out[2 * t + 1] = pack4(v1.x, v1.y, v1.z, v1.w, scale, -128.f, 127.f);
  if (t == 0) ascale[row] = am / 127.0f;
}

// ---------------------------------------------------------------- act quant (h: rows of 8192)

__global__ __launch_bounds__(256) void quant_h_kernel(
    const float* __restrict__ h, signed char* __restrict__ hq,
    float* __restrict__ ascale) {
  int row = blockIdx.x;
  const float4* hr = (const float4*)(h + (size_t)row * HH);
  int t = threadIdx.x;
  float4 v[8];
  float m = 0.f;
  #pragma unroll
  for (int i = 0; i < 8; i++) {
    v[i] = hr[t + i * 256];
    m = fmaxf(m, fmaxf(fmaxf(fabsf(v[i].x), fabsf(v[i].y)),
                       fmaxf(fabsf(v[i].z), fabsf(v[i].w))));
  }
  float am = fmaxf(blockMax256(m), EPSF);
  float scale = 127.0f / am;
  int* out = (int*)(hq + (size_t)row * HH);
  #pragma unroll
  for (int i = 0; i < 8; i++)
    out[t + i * 256] = pack4(v[i].x, v[i].y, v[i].z, v[i].w, scale, -128.f, 127.f);
  if (t == 0) ascale[row] = am / 127.0f;
}

// ---------------------------------------------------------------- int8 GEMM
// C[M][N] = sum_k A[M][K] * B[N][K]   (both int8, K contiguous)
// 128x128 tile, BK=128 bytes, 4 waves (2x2), each 64x64 via 4x4 mfma 16x16x64.
// LDS layout: row-major [128][128] with 16B-chunk XOR swizzle c ^= (r&7).

template <int RELU>
__global__ __launch_bounds__(256) void gemm_i8_kernel(
    const signed char* __restrict__ A, const signed char* __restrict__ B,
    float* __restrict__ C, const float* __restrict__ ascale,
    const double* __restrict__ wsum, int M, int N, int K) {
  __shared__ signed char As[128 * 128];
  __shared__ signed char Bs[128 * 128];

  const int t = threadIdx.x;
  const int lane = t & 63, wv = t >> 6;
  const int wm = wv >> 1, wn = wv & 1;
  const int m0 = blockIdx.y * 128, n0 = blockIdx.x * 128;
  const int q = lane >> 4;

  // staging: 16 segments of 1024B (8 rows x 128B); wave wv covers segs wv*4..wv*4+3
  const int segBase = wv * 4;
  const signed char* aSrc[4];
  const signed char* bSrc[4];
  #pragma unroll
  for (int i = 0; i < 4; i++) {
    int seg = segBase + i;
    int r = seg * 8 + (lane >> 3);
    int c = (lane & 7) ^ (r & 7);
    aSrc[i] = A + (size_t)(m0 + r) * K + c * 16;
    bSrc[i] = B + (size_t)(n0 + r) * K + c * 16;
  }

  v4i acc[4][4];
  #pragma unroll
  for (int i = 0; i < 4; i++)
    #pragma unroll
    for (int j = 0; j < 4; j++) {
      v4i z = {0, 0, 0, 0};
      acc[i][j] = z;
    }

  int rowA[4], rowB[4];
  #pragma unroll
  for (int i = 0; i < 4; i++) {
    rowA[i] = wm * 64 + i * 16 + (lane & 15);
    rowB[i] = wn * 64 + i * 16 + (lane & 15);
  }

  for (int k0 = 0; k0 < K; k0 += 128) {
    #pragma unroll
    for (int i = 0; i < 4; i++) {
      async_copy16(aSrc[i] + k0, &As[(segBase + i) * 1024]);
      async_copy16(bSrc[i] + k0, &Bs[(segBase + i) * 1024]);
    }
    __syncthreads();
    #pragma unroll
    for (int kc = 0; kc < 2; kc++) {
      v4i af[4], bf[4];
      #pragma unroll
      for (int i = 0; i < 4; i++) {
        int ca = (kc * 4 + q) ^ (rowA[i] & 7);
        af[i] = *(const v4i*)(As + rowA[i] * 128 + ca * 16);
        int cb = (kc * 4 + q) ^ (rowB[i] & 7);
        bf[i] = *(const v4i*)(Bs + rowB[i] * 128 + cb * 16);
      }
      #pragma unroll
      for (int i = 0; i < 4; i++)
        #pragma unroll
        for (int j = 0; j < 4; j++)
          acc[i][j] = __builtin_amdgcn_mfma_i32_16x16x64_i8(af[i], bf[j], acc[i][j], 0, 0, 0);
    }
    __syncthreads();
  }

  float wmean = fmaxf((float)(wsum[0] * (1.0 / (double)WCOUNT)), EPSF);
  #pragma unroll
  for (int i = 0; i < 4; i++) {
    int mBase = m0 + wm * 64 + i * 16 + q * 4;
    #pragma unroll
    for (int e = 0; e < 4; e++) {
      float f = ascale[mBase + e] * wmean;
      #pragma unroll
      for (int j = 0; j < 4; j++) {
        int n = n0 + wn * 64 + j * 16 + (lane & 15);
        float v = (float)acc[i][j][e] * f;
        if (RELU) v = fmaxf(v, 0.f);
        C[(size_t)(mBase + e) * N + n] = v;
      }
    }
  }
}

// ---------------------------------------------------------------- launch

extern "C" void kernel_launch(void* const* d_in, const int* in_sizes, int n_in,
                              void* d_out, int out_size, void* d_ws, size_t ws_size,
                              hipStream_t stream) {
  const float* x  = (const float*)d_in[0];
  const float* w1 = (const float*)d_in[1];
  const float* w2 = (const float*)d_in[2];
  float* out = (float*)d_out;

  char* ws = (char*)d_ws;
  double* sums = (double*)ws;                                // 16 B
  float* a1 = (float*)(ws + 256);                            // 4096 f32
  float* a2 = (float*)(ws + 256 + 16384);                    // 4096 f32
  signed char* w1q = (signed char*)(ws + 33024);             // 16 MB
  signed char* w2q = w1q + (size_t)WCOUNT;                   // 16 MB
  signed char* xq  = w2q + (size_t)WCOUNT;                   // 8 MB
  signed char* hq  = xq + (size_t)MROWS * DD;                // 32 MB
  float* h = (float*)(hq + (size_t)MROWS * HH);              // 128 MB fp32

  hipMemsetAsync(sums, 0, 16, stream);
  abs_sum_kernel<<<dim3(1024, 2), 256, 0, stream>>>(w1, w2, sums);
  quant_w_kernel<<<dim3(2048, 2), 256, 0, stream>>>(w1, w2, sums, w1q, w2q);
  quant_x_kernel<<<MROWS, 256, 0, stream>>>(x, xq, a1);
  gemm_i8_kernel<1><<<dim3(HH / 128, MROWS / 128), 256, 0, stream>>>(
      xq, w1q, h, a1, &sums[0], MROWS, HH, DD);
  quant_h_kernel<<<MROWS, 256, 0, stream>>>(h, hq, a2);
  gemm_i8_kernel<0><<<dim3(DD / 128, MROWS / 128), 256, 0, stream>>>(
      hq, w2q, out, a2, &sums[1], MROWS, DD, HH);
}

// Round 2
// 389.910 us; speedup vs baseline: 1.0749x; 1.0749x over previous
//
#include <hip/hip_runtime.h>
#include <hip/hip_bf16.h>

#define EPSF 1e-5f

typedef int v4i __attribute__((ext_vector_type(4)));
typedef short v8s __attribute__((ext_vector_type(8)));

static constexpr int BB = 4, TT = 1024, DD = 2048, HH = 8192;
static constexpr int MROWS = BB * TT;                   // 4096
static constexpr long long WCOUNT = (long long)DD * HH; // 2^24 elements per weight

// ---------------------------------------------------------------- helpers

__device__ __forceinline__ void async_copy16(const void* g, void* l) {
  __builtin_amdgcn_global_load_lds(
      (const __attribute__((address_space(1))) unsigned int*)g,
      (__attribute__((address_space(3))) unsigned int*)l,
      16, 0, 0);
}

__device__ __forceinline__ int pack4(float a, float b, float c, float d,
                                     float scale, float lo, float hi) {
  int ia = (int)fminf(fmaxf(rintf(a * scale), lo), hi);
  int ib = (int)fminf(fmaxf(rintf(b * scale), lo), hi);
  int ic = (int)fminf(fmaxf(rintf(c * scale), lo), hi);
  int id = (int)fminf(fmaxf(rintf(d * scale), lo), hi);
  return (ia & 0xff) | ((ib & 0xff) << 8) | ((ic & 0xff) << 16) | ((id & 0xff) << 24);
}

__device__ __forceinline__ float blockMaxF256(float v) {
  #pragma unroll
  for (int off = 32; off; off >>= 1) v = fmaxf(v, __shfl_down(v, off, 64));
  __shared__ float sm[4];
  int lane = threadIdx.x & 63, wv = threadIdx.x >> 6;
  if (lane == 0) sm[wv] = v;
  __syncthreads();
  return fmaxf(fmaxf(sm[0], sm[1]), fmaxf(sm[2], sm[3]));
}

__device__ __forceinline__ int blockMaxI256(int v) {
  #pragma unroll
  for (int off = 32; off; off >>= 1) v = max(v, __shfl_down(v, off, 64));
  __shared__ int sm[4];
  int lane = threadIdx.x & 63, wv = threadIdx.x >> 6;
  if (lane == 0) sm[wv] = v;
  __syncthreads();
  return max(max(sm[0], sm[1]), max(sm[2], sm[3]));
}

// XCD-aware tile swizzle: linear block id -> (mt, nt) such that each id%8
// class (heuristic XCD assignment) owns a contiguous 2D patch of tiles.
__device__ __forceinline__ void swizzle_tiles(int& mt, int& nt) {
  int Mt = gridDim.y, Nt = gridDim.x;
  int id = blockIdx.y * Nt + blockIdx.x;
  int c = id & 7, k = id >> 3;
  int pm = (Mt >= Nt) ? 4 : 2;   // patch grid: pm x (8/pm)
  int PM = Mt / pm, PN = Nt / (8 / pm);
  int pr = c % pm, pc = c / pm;
  mt = pr * PM + (k % PM);
  nt = pc * PN + (k / PM);
}

// ---------------------------------------------------------------- mean|w|

__global__ __launch_bounds__(256) void abs_sum_kernel(
    const float* __restrict__ w1, const float* __restrict__ w2,
    double* __restrict__ sums) {
  const float* w = blockIdx.y ? w2 : w1;
  const float4* w4 = (const float4*)w;
  long long n4 = WCOUNT / 4;
  float s = 0.f;
  for (long long i = (long long)blockIdx.x * blockDim.x + threadIdx.x; i < n4;
       i += (long long)gridDim.x * blockDim.x) {
    float4 v = w4[i];
    s += fabsf(v.x) + fabsf(v.y) + fabsf(v.z) + fabsf(v.w);
  }
  #pragma unroll
  for (int off = 32; off; off >>= 1) s += __shfl_down(s, off, 64);
  __shared__ float sm[4];
  int lane = threadIdx.x & 63, wv = threadIdx.x >> 6;
  if (lane == 0) sm[wv] = s;
  __syncthreads();
  if (threadIdx.x == 0) {
    float t = sm[0] + sm[1] + sm[2] + sm[3];
    atomicAdd(&sums[blockIdx.y], (double)t);
  }
}

// ---------------------------------------------------------------- ternary quant

__global__ __launch_bounds__(256) void quant_w_kernel(
    const float* __restrict__ w1, const float* __restrict__ w2,
    const double* __restrict__ sums,
    signed char* __restrict__ q1, signed char* __restrict__ q2) {
  const float* w = blockIdx.y ? w2 : w1;
  signed char* q = blockIdx.y ? q2 : q1;
  float mean = fmaxf((float)(sums[blockIdx.y] * (1.0 / (double)WCOUNT)), EPSF);
  float scale = 1.0f / mean;
  const float4* w4 = (const float4*)w;
  int* q4 = (int*)q;
  long long n4 = WCOUNT / 4;
  for (long long i = (long long)blockIdx.x * blockDim.x + threadIdx.x; i < n4;
       i += (long long)gridDim.x * blockDim.x) {
    float4 v = w4[i];
    q4[i] = pack4(v.x, v.y, v.z, v.w, scale, -1.f, 1.f);
  }
}

// ---------------------------------------------------------------- act quant x

__global__ __launch_bounds__(256) void quant_x_kernel(
    const float* __restrict__ x, signed char* __restrict__ xq,
    float* __restrict__ ascale) {
  int row = blockIdx.x;
  const float4* xr = (const float4*)(x + (size_t)row * DD);
  int t = threadIdx.x;
  float4 v0 = xr[2 * t], v1 = xr[2 * t + 1];
  float m = fmaxf(fmaxf(fabsf(v0.x), fabsf(v0.y)), fmaxf(fabsf(v0.z), fabsf(v0.w)));
  m = fmaxf(m, fmaxf(fmaxf(fabsf(v1.x), fabsf(v1.y)), fmaxf(fabsf(v1.z), fabsf(v1.w))));
  float am = fmaxf(blockMaxF256(m), EPSF);
  float scale = 127.0f / am;
  int* out = (int*)(xq + (size_t)row * DD);
  out[2 * t]     = pack4(v0.x, v0.y, v0.z, v0.w, scale, -128.f, 127.f);
  out[2 * t + 1] = pack4(v1.x, v1.y, v1.z, v1.w, scale, -128.f, 127.f);
  if (t == 0) ascale[row] = am / 127.0f;
}

// ---------------------------------------------------------------- act quant h (int16 in)

__global__ __launch_bounds__(256) void quant_h_kernel(
    const short* __restrict__ h, signed char* __restrict__ hq,
    float* __restrict__ a2, const float* __restrict__ a1,
    const double* __restrict__ sums) {
  int row = blockIdx.x;
  int t = threadIdx.x;
  const v8s* hr = (const v8s*)(h + (size_t)row * HH);  // 1024 vecs of 8 shorts
  v8s v[4];
  int mx = 0;
  #pragma unroll
  for (int i = 0; i < 4; i++) {
    v[i] = hr[t + i * 256];
    #pragma unroll
    for (int j = 0; j < 8; j++) mx = max(mx, (int)v[i][j]);
  }
  int bmx = blockMaxI256(mx);
  float wmean1 = fmaxf((float)(sums[0] * (1.0 / (double)WCOUNT)), EPSF);
  float f = a1[row] * wmean1;           // per-row dequant factor (exact ref path)
  float maxh = (float)bmx * f;          // == max_j fl(r_j * f) (fl monotone, f>=0)
  float am = fmaxf(maxh, EPSF);
  float scale = 127.0f / am;
  int* out = (int*)(hq + (size_t)row * HH);
  #pragma unroll
  for (int i = 0; i < 4; i++) {
    out[(t + i * 256) * 2] =
        pack4((float)v[i][0] * f, (float)v[i][1] * f, (float)v[i][2] * f,
              (float)v[i][3] * f, scale, -128.f, 127.f);
    out[(t + i * 256) * 2 + 1] =
        pack4((float)v[i][4] * f, (float)v[i][5] * f, (float)v[i][6] * f,
              (float)v[i][7] * f, scale, -128.f, 127.f);
  }
  if (t == 0) a2[row] = am / 127.0f;
}

// ---------------------------------------------------------------- int8 GEMM
// C[M][N] = sum_k A[M][K]*B[N][K], int8, K contiguous. 128x128 tile, 4 waves
// 2x2, each 64x64 via 4x4 mfma_i32_16x16x64_i8. XOR 16B-chunk swizzle -> 0
// LDS bank conflicts (verified round 1). MODE 1: relu -> int16 store (exact).
// MODE 0: scaled fp32 store.

template <int MODE, int BK>
__global__ __launch_bounds__(256) void gemm_i8_kernel(
    const signed char* __restrict__ A, const signed char* __restrict__ B,
    void* __restrict__ Cout, const float* __restrict__ ascale,
    const double* __restrict__ wsum, int M, int N, int K) {
  constexpr int CH = BK / 16;        // 16B chunks per LDS row
  constexpr int SEGROWS = 1024 / BK; // rows per 1KB staging segment
  constexpr int SPW = BK / 32;       // segments per wave per matrix
  __shared__ signed char As[128 * BK];
  __shared__ signed char Bs[128 * BK];

  const int t = threadIdx.x;
  const int lane = t & 63, wv = t >> 6;
  const int wm = wv >> 1, wn = wv & 1;
  int mt, nt;
  swizzle_tiles(mt, nt);
  const int m0 = mt * 128, n0 = nt * 128;
  const int q = lane >> 4;

  const signed char* aSrc[SPW];
  const signed char* bSrc[SPW];
  #pragma unroll
  for (int i = 0; i < SPW; i++) {
    int seg = wv * SPW + i;
    int r = seg * SEGROWS + lane / CH;
    int c = (lane % CH) ^ (r & (CH - 1));
    aSrc[i] = A + (size_t)(m0 + r) * K + c * 16;
    bSrc[i] = B + (size_t)(n0 + r) * K + c * 16;
  }

  v4i acc[4][4];
  #pragma unroll
  for (int i = 0; i < 4; i++)
    #pragma unroll
    for (int j = 0; j < 4; j++) {
      v4i z = {0, 0, 0, 0};
      acc[i][j] = z;
    }

  int rowA[4], rowB[4];
  #pragma unroll
  for (int i = 0; i < 4; i++) {
    rowA[i] = wm * 64 + i * 16 + (lane & 15);
    rowB[i] = wn * 64 + i * 16 + (lane & 15);
  }

  for (int k0 = 0; k0 < K; k0 += BK) {
    #pragma unroll
    for (int i = 0; i < SPW; i++) {
      async_copy16(aSrc[i] + k0, &As[(wv * SPW + i) * 1024]);
      async_copy16(bSrc[i] + k0, &Bs[(wv * SPW + i) * 1024]);
    }
    __syncthreads();
    #pragma unroll
    for (int kc = 0; kc < CH / 4; kc++) {
      v4i af[4], bf[4];
      #pragma unroll
      for (int i = 0; i < 4; i++) {
        int ca = (kc * 4 + q) ^ (rowA[i] & (CH - 1));
        af[i] = *(const v4i*)(As + rowA[i] * BK + ca * 16);
        int cb = (kc * 4 + q) ^ (rowB[i] & (CH - 1));
        bf[i] = *(const v4i*)(Bs + rowB[i] * BK + cb * 16);
      }
      #pragma unroll
      for (int i = 0; i < 4; i++)
        #pragma unroll
        for (int j = 0; j < 4; j++)
          acc[i][j] = __builtin_amdgcn_mfma_i32_16x16x64_i8(af[i], bf[j], acc[i][j], 0, 0, 0);
    }
    __syncthreads();
  }

  if constexpr (MODE == 1) {
    short* C = (short*)Cout;
    #pragma unroll
    for (int i = 0; i < 4; i++) {
      int mBase = m0 + wm * 64 + i * 16 + q * 4;
      #pragma unroll
      for (int e = 0; e < 4; e++) {
        #pragma unroll
        for (int j = 0; j < 4; j++) {
          int n = n0 + wn * 64 + j * 16 + (lane & 15);
          int r = acc[i][j][e];
          r = r < 0 ? 0 : (r > 32767 ? 32767 : r);
          C[(size_t)(mBase + e) * N + n] = (short)r;
        }
      }
    }
  } else {
    float* C = (float*)Cout;
    float wmean = fmaxf((float)(wsum[0] * (1.0 / (double)WCOUNT)), EPSF);
    #pragma unroll
    for (int i = 0; i < 4; i++) {
      int mBase = m0 + wm * 64 + i * 16 + q * 4;
      #pragma unroll
      for (int e = 0; e < 4; e++) {
        float f = ascale[mBase + e] * wmean;
        #pragma unroll
        for (int j = 0; j < 4; j++) {
          int n = n0 + wn * 64 + j * 16 + (lane & 15);
          C[(size_t)(mBase + e) * N + n] = (float)acc[i][j][e] * f;
        }
      }
    }
  }
}

// ---------------------------------------------------------------- launch

extern "C" void kernel_launch(void* const* d_in, const int* in_sizes, int n_in,
                              void* d_out, int out_size, void* d_ws, size_t ws_size,
                              hipStream_t stream) {
  const float* x  = (const float*)d_in[0];
  const float* w1 = (const float*)d_in[1];
  const float* w2 = (const float*)d_in[2];
  float* out = (float*)d_out;

  char* ws = (char*)d_ws;
  double* sums = (double*)ws;                               // 16 B
  float* a1 = (float*)(ws + 256);                           // 4096 f32
  float* a2 = (float*)(ws + 256 + 16384);                   // 4096 f32
  signed char* w1q = (signed char*)(ws + 33024);            // 16 MB
  signed char* w2q = w1q + (size_t)WCOUNT;                  // 16 MB
  signed char* xq  = w2q + (size_t)WCOUNT;                  // 8 MB
  signed char* hq  = xq + (size_t)MROWS * DD;               // 32 MB
  short* h16 = (short*)(hq + (size_t)MROWS * HH);           // 64 MB int16

  hipMemsetAsync(sums, 0, 16, stream);
  abs_sum_kernel<<<dim3(1024, 2), 256, 0, stream>>>(w1, w2, sums);
  quant_w_kernel<<<dim3(2048, 2), 256, 0, stream>>>(w1, w2, sums, w1q, w2q);
  quant_x_kernel<<<MROWS, 256, 0, stream>>>(x, xq, a1);
  gemm_i8_kernel<1, 128><<<dim3(HH / 128, MROWS / 128), 256, 0, stream>>>(
      xq, w1q, h16, nullptr, nullptr, MROWS, HH, DD);
  quant_h_kernel<<<MROWS, 256, 0, stream>>>(h16, hq, a2, a1, sums);
  gemm_i8_kernel<0, 256><<<dim3(DD / 128, MROWS / 128), 256, 0, stream>>>(
      hq, w2q, out, a2, &sums[1], MROWS, DD, HH);
}